// Round 6
// baseline (181.063 us; speedup 1.0000x reference)
//
#include <hip/hip_runtime.h>

#define HH 256
#define WW 256
#define HWSZ (HH * WW)

// Groups of 4 points. Each block handles CHUNK_GROUPS groups (2048 points):
// 256 threads x 2 iterations x 4 points. 245 blocks/batch x 8 batches.
#define CHUNK_GROUPS 512
#define NSLOTS 1020   // border pixels: 2*256 (top/bottom rows) + 2*254 (side cols)
#define SLOTPAD 1024  // padded to 1024 for float4 stores

// Border slot encoding (gapless, injective — R5 post-mortem: the old
// 766+v encoding collided slot 767 onto a decode that wrote one pixel
// PAST the batch image; as atomics it was benign-looking, as plain
// stores it raced with the next batch's corner):
//   v==0          -> slot u          (0..255)
//   v==255        -> slot 256+u      (256..511)
//   u==0, 1<=v<255 -> slot 511+v     (512..765)
//   u==255,1<=v<255 -> slot 765+v    (766..1019)
//
// Contention structure (x/z, y/z are Cauchy): ~35.4% clamp low / 35.4% clamp
// high per axis -> 4 corner pixels get ~50% of accepted points (register
// pre-reduction), border edges ~41% (LDS histogram), interior ~9% (direct
// global atomics over 65k addresses). R4 post-mortem: flushing the LDS
// histogram with global ATOMICS concentrated ~690k L2 RMWs on 512 cache
// lines -> ~48us serialization. Fix: plain coalesced stores of each block's
// histogram to scratch; merge_k reduces and plain-stores into flat (border
// pixels receive no interior atomics, so no atomicity needed).
__global__ __launch_bounds__(256) void scatter_k(
    const float* __restrict__ pts, const float* __restrict__ dens,
    float* __restrict__ flat, float* __restrict__ scratch, int N, int cb)
{
    __shared__ float lds[SLOTPAD];
    for (int s = threadIdx.x; s < SLOTPAD; s += 256) lds[s] = 0.0f;
    __syncthreads();

    int b = blockIdx.y;
    const float* pb = pts + (size_t)b * N * 3;
    const float* db = dens + (size_t)b * N;
    float* out = flat + (size_t)b * HWSZ;

    int ngroups = N >> 2;  // N divisible by 4 (500000)
    int gbase = blockIdx.x * CHUNK_GROUPS;
    const float4* p4 = (const float4*)pb;
    const float4* d4 = (const float4*)db;

    // Per-thread register accumulators for the 4 corner pixels.
    // idx = (v==255 ? 2 : 0) | (u==255 ? 1 : 0); LDS slots {0,255,256,511}.
    float corner[4] = {0.0f, 0.0f, 0.0f, 0.0f};

    #pragma unroll
    for (int it = 0; it < CHUNK_GROUPS / 256; it++) {
        int g = gbase + it * 256 + threadIdx.x;
        if (g >= ngroups) continue;

        float4 a  = p4[3 * g];
        float4 bb = p4[3 * g + 1];
        float4 c  = p4[3 * g + 2];
        float4 dd = d4[g];

        float xs[4] = {a.x, a.w, bb.z, c.y};
        float ys[4] = {a.y, bb.x, bb.w, c.z};
        float zs[4] = {a.z, bb.y, c.x, c.w};
        float ds[4] = {dd.x, dd.y, dd.z, dd.w};

        #pragma unroll
        for (int k = 0; k < 4; k++) {
            float d = ds[k];
            if (d > 0.5f) {
                float z = zs[k];
                // ref: clip(int32((x/z + 0.5) * 256), 0, 255)
                // trunc-toward-zero then clip == clamp-in-float then trunc
                // (holds for negatives, overflow->inf, and NaN->0).
                float uf = (xs[k] / z + 0.5f) * 256.0f;
                float vf = (ys[k] / z + 0.5f) * 256.0f;
                int u = (int)fminf(fmaxf(uf, 0.0f), 255.0f);
                int v = (int)fminf(fmaxf(vf, 0.0f), 255.0f);
                float val = z * d;
                bool ub = (u == 0) | (u == 255);
                bool vb = (v == 0) | (v == 255);
                if (ub & vb) {
                    corner[((v == 255) ? 2 : 0) | ((u == 255) ? 1 : 0)] += val;
                } else if (v == 0) {
                    atomicAdd(&lds[u], val);
                } else if (v == 255) {
                    atomicAdd(&lds[256 + u], val);
                } else if (u == 0) {
                    atomicAdd(&lds[511 + v], val);
                } else if (u == 255) {
                    atomicAdd(&lds[765 + v], val);
                } else {
                    atomicAdd(out + v * WW + u, val);
                }
            }
        }
    }

    // Wave-reduce the 4 corner accumulators; one LDS add per wave per corner.
    #pragma unroll
    for (int j = 0; j < 4; j++) {
        float v = corner[j];
        #pragma unroll
        for (int off = 32; off > 0; off >>= 1) v += __shfl_down(v, off);
        if ((threadIdx.x & 63) == 0) {
            const int cslot[4] = {0, 255, 256, 511};
            atomicAdd(&lds[cslot[j]], v);
        }
    }

    __syncthreads();
    // Plain coalesced float4 store of the whole histogram (NO atomics).
    float4* dst = (float4*)(scratch + ((size_t)b * cb + blockIdx.x) * SLOTPAD);
    const float4* src = (const float4*)lds;
    dst[threadIdx.x] = src[threadIdx.x];
}

// Sum the cb per-block histograms for each (batch, slot) and plain-store
// into flat. Loads are coalesced across lanes (consecutive slots adjacent).
// Exact inverse of the slot encoding above; skips pad slots >= NSLOTS.
__global__ __launch_bounds__(256) void merge_k(
    const float* __restrict__ scratch, float* __restrict__ flat, int cb)
{
    int b = blockIdx.x >> 2;                     // 4 blocks per batch
    int s = (blockIdx.x & 3) * 256 + threadIdx.x;
    if (s >= NSLOTS) return;
    const float* base = scratch + (size_t)b * cb * SLOTPAD + s;
    float s0 = 0.0f, s1 = 0.0f, s2 = 0.0f, s3 = 0.0f;
    int j = 0;
    for (; j + 4 <= cb; j += 4) {
        s0 += base[(size_t)(j + 0) * SLOTPAD];
        s1 += base[(size_t)(j + 1) * SLOTPAD];
        s2 += base[(size_t)(j + 2) * SLOTPAD];
        s3 += base[(size_t)(j + 3) * SLOTPAD];
    }
    for (; j < cb; j++) s0 += base[(size_t)j * SLOTPAD];
    float sum = (s0 + s1) + (s2 + s3);

    int u, vv;
    if (s < 256)      { vv = 0;   u = s; }
    else if (s < 512) { vv = 255; u = s - 256; }
    else if (s < 766) { u = 0;    vv = s - 511; }
    else              { u = 255;  vv = s - 765; }
    flat[(size_t)b * HWSZ + vv * WW + u] = sum;  // no interior atomics hit border
}

// Fused masked-MSE reduction + finalize. float4 grid-stride; wave shuffle
// reduce; one atomic per wave into accum[0]=sum(float), accum[1]=count(int).
// Last finishing block (device-scope done counter) computes out[0].
__global__ __launch_bounds__(256) void loss_k(
    const float* __restrict__ flat, const float* __restrict__ depth,
    float* __restrict__ accum, int* __restrict__ done,
    float* __restrict__ out, int total4, int nblocks)
{
    const float4* f4 = (const float4*)flat;
    const float4* z4 = (const float4*)depth;
    float s = 0.0f;
    int c = 0;
    for (int i = blockIdx.x * blockDim.x + threadIdx.x; i < total4;
         i += gridDim.x * blockDim.x) {
        float4 p = f4[i];
        float4 q = z4[i];
        if (p.x > 0.0f) { float df = p.x - q.x; s += df * df; c++; }
        if (p.y > 0.0f) { float df = p.y - q.y; s += df * df; c++; }
        if (p.z > 0.0f) { float df = p.z - q.z; s += df * df; c++; }
        if (p.w > 0.0f) { float df = p.w - q.w; s += df * df; c++; }
    }
    #pragma unroll
    for (int off = 32; off > 0; off >>= 1) {
        s += __shfl_down(s, off);
        c += __shfl_down(c, off);
    }
    if ((threadIdx.x & 63) == 0) {
        atomicAdd(accum, s);
        atomicAdd((int*)accum + 1, c);
    }
    __syncthreads();
    if (threadIdx.x == 0) {
        __threadfence();
        int old = atomicAdd(done, 1);
        if (old == nblocks - 1) {
            // L2-coherent reads of the final totals.
            float ts = atomicAdd(accum, 0.0f);
            int tc = atomicAdd((int*)accum + 1, 0);
            out[0] = ts / (float)(tc >= 1 ? tc : 1);
        }
    }
}

extern "C" void kernel_launch(void* const* d_in, const int* in_sizes, int n_in,
                              void* d_out, int out_size, void* d_ws, size_t ws_size,
                              hipStream_t stream) {
    const float* pts   = (const float*)d_in[0];  // (B, N, 3)
    const float* dens  = (const float*)d_in[1];  // (B, N, 1)
    const float* depth = (const float*)d_in[2];  // (B, 1, H, W)
    float* out = (float*)d_out;

    int B = in_sizes[2] / HWSZ;           // 8
    int N = in_sizes[0] / (3 * B);        // 500000

    int ngroups = N / 4;
    int cb = (ngroups + CHUNK_GROUPS - 1) / CHUNK_GROUPS;  // 245 blocks/batch

    float* flat    = (float*)d_ws;                     // B*HW floats
    float* accum   = flat + (size_t)B * HWSZ;          // [sum(float), count(int)]
    int*   done    = (int*)(accum + 2);
    float* scratch = accum + 4;                        // B*cb*SLOTPAD floats (~8 MB)

    // ws is re-poisoned to 0xAA before every launch: zero flat+accum+done.
    // scratch needs no zeroing (every slot is overwritten by scatter_k).
    hipMemsetAsync(d_ws, 0, ((size_t)B * HWSZ + 4) * sizeof(float), stream);

    dim3 sgrid(cb, B);
    scatter_k<<<sgrid, 256, 0, stream>>>(pts, dens, flat, scratch, N, cb);

    merge_k<<<dim3(4 * B), 256, 0, stream>>>(scratch, flat, cb);

    int total4 = B * HWSZ / 4;
    int lblocks = 256;
    loss_k<<<dim3(lblocks), 256, 0, stream>>>(flat, depth, accum, done, out,
                                              total4, lblocks);
}

// Round 7
// 158.448 us; speedup vs baseline: 1.1427x; 1.1427x over previous
//
#include <hip/hip_runtime.h>

#define HH 256
#define WW 256
#define HWSZ (HH * WW)

// Groups of 4 points. Each block handles CHUNK_GROUPS groups (2048 points):
// 256 threads x 2 iterations x 4 points. 245 blocks/batch x 8 batches.
#define CHUNK_GROUPS 512
#define NSLOTS 1020   // border pixels: 2*256 (rows 0,255) + 2*254 (cols 0,255)
#define SLOTPAD 1024  // padded to 1024 for float4 stores

// Border slot encoding (gapless, injective):
//   v==0            -> slot u        (0..255)    corners (0,0)->0,(255,0)->255
//   v==255          -> slot 256+u    (256..511)  corners (0,255)->256,(255,255)->511
//   u==0,  1<=v<255 -> slot 511+v    (512..765)
//   u==255,1<=v<255 -> slot 765+v    (766..1019)
//
// Contention structure (x/z, y/z are Cauchy): 4 corners get ~50% of accepted
// points (register pre-reduction), border edges ~41% (LDS histogram via ONE
// computed-slot ds_atomic — R6 post-mortem: the old 6-way divergent branch
// with 5 memory arms serializes every wave through every arm), interior ~9%
// (direct global atomics over 65k addresses, negligible chains).
__global__ __launch_bounds__(256) void scatter_k(
    const float* __restrict__ pts, const float* __restrict__ dens,
    float* __restrict__ flat, float* __restrict__ scratch, int N, int cb)
{
    __shared__ float lds[SLOTPAD];
    for (int s = threadIdx.x; s < SLOTPAD; s += 256) lds[s] = 0.0f;
    __syncthreads();

    int b = blockIdx.y;
    const float* pb = pts + (size_t)b * N * 3;
    const float* db = dens + (size_t)b * N;
    float* out = flat + (size_t)b * HWSZ;

    int ngroups = N >> 2;  // N divisible by 4 (500000)
    int gbase = blockIdx.x * CHUNK_GROUPS;
    const float4* p4 = (const float4*)pb;
    const float4* d4 = (const float4*)db;

    // Per-thread register accumulators for the 4 corner pixels.
    // idx = (v==255 ? 2 : 0) | (u==255 ? 1 : 0).
    float corner[4] = {0.0f, 0.0f, 0.0f, 0.0f};

    #pragma unroll
    for (int it = 0; it < CHUNK_GROUPS / 256; it++) {
        int g = gbase + it * 256 + threadIdx.x;
        if (g >= ngroups) continue;

        float4 a  = p4[3 * g];
        float4 bb = p4[3 * g + 1];
        float4 c  = p4[3 * g + 2];
        float4 dd = d4[g];

        float xs[4] = {a.x, a.w, bb.z, c.y};
        float ys[4] = {a.y, bb.x, bb.w, c.z};
        float zs[4] = {a.z, bb.y, c.x, c.w};
        float ds[4] = {dd.x, dd.y, dd.z, dd.w};

        #pragma unroll
        for (int k = 0; k < 4; k++) {
            float d = ds[k];
            if (d > 0.5f) {
                float z = zs[k];
                // ref: clip(int32((x/z + 0.5) * 256), 0, 255)
                // trunc-toward-zero then clip == clamp-in-float then trunc
                // (holds for negatives, overflow->inf, and NaN->0).
                float uf = (xs[k] / z + 0.5f) * 256.0f;
                float vf = (ys[k] / z + 0.5f) * 256.0f;
                int u = (int)fminf(fmaxf(uf, 0.0f), 255.0f);
                int v = (int)fminf(fmaxf(vf, 0.0f), 255.0f);
                float val = z * d;
                bool ub = (u == 0) | (u == 255);
                bool vb = (v == 0) | (v == 255);
                if (ub & vb) {
                    corner[((v == 255) ? 2 : 0) | ((u == 255) ? 1 : 0)] += val;
                } else if (ub | vb) {
                    // single computed slot, single ds_atomic site
                    int slot = vb ? (((v != 0) << 8) + u)
                                  : ((u ? 765 : 511) + v);
                    atomicAdd(&lds[slot], val);
                } else {
                    atomicAdd(out + v * WW + u, val);
                }
            }
        }
    }

    // Wave-reduce the 4 corner accumulators; one LDS add per wave per corner.
    #pragma unroll
    for (int j = 0; j < 4; j++) {
        float v = corner[j];
        #pragma unroll
        for (int off = 32; off > 0; off >>= 1) v += __shfl_down(v, off);
        if ((threadIdx.x & 63) == 0) {
            const int cslot[4] = {0, 255, 256, 511};
            atomicAdd(&lds[cslot[j]], v);
        }
    }

    __syncthreads();
    // Plain coalesced float4 store of the whole histogram (NO atomics).
    float4* dst = (float4*)(scratch + ((size_t)b * cb + blockIdx.x) * SLOTPAD);
    const float4* src = (const float4*)lds;
    dst[threadIdx.x] = src[threadIdx.x];
}

// Fused border-merge + masked-MSE + finalize.
// Part A: each of the first B*NSLOTS threads sums ONE border slot across the
//         cb per-block histograms (coalesced across lanes) and adds that
//         pixel's loss contribution directly — no flat round-trip.
// Part B: grid-stride float4 over flat, SKIPPING border pixels (row 0/255
//         quads entirely; elements x/w of the col-0/col-255 quads).
// Wave shuffle reduce -> one atomic per wave; last block (done counter)
// finalizes out[0].
__global__ __launch_bounds__(256) void loss_k(
    const float* __restrict__ flat, const float* __restrict__ depth,
    const float* __restrict__ scratch,
    float* __restrict__ accum, int* __restrict__ done,
    float* __restrict__ out, int B, int cb, int nblocks)
{
    int tid = blockIdx.x * 256 + threadIdx.x;
    int nthreads = gridDim.x * 256;
    float s = 0.0f;
    int c = 0;

    // ---- Part A: border pixels from scratch histograms ----
    for (int idx = tid; idx < B * NSLOTS; idx += nthreads) {
        int b = idx / NSLOTS;
        int sl = idx - b * NSLOTS;
        const float* base = scratch + (size_t)b * cb * SLOTPAD + sl;
        float a0 = 0, a1 = 0, a2 = 0, a3 = 0, a4 = 0, a5 = 0, a6 = 0, a7 = 0;
        int j = 0;
        for (; j + 8 <= cb; j += 8) {
            a0 += base[(size_t)(j + 0) * SLOTPAD];
            a1 += base[(size_t)(j + 1) * SLOTPAD];
            a2 += base[(size_t)(j + 2) * SLOTPAD];
            a3 += base[(size_t)(j + 3) * SLOTPAD];
            a4 += base[(size_t)(j + 4) * SLOTPAD];
            a5 += base[(size_t)(j + 5) * SLOTPAD];
            a6 += base[(size_t)(j + 6) * SLOTPAD];
            a7 += base[(size_t)(j + 7) * SLOTPAD];
        }
        for (; j < cb; j++) a0 += base[(size_t)j * SLOTPAD];
        float sum = ((a0 + a1) + (a2 + a3)) + ((a4 + a5) + (a6 + a7));

        int u, v;
        if (sl < 256)      { v = 0;   u = sl; }
        else if (sl < 512) { v = 255; u = sl - 256; }
        else if (sl < 766) { u = 0;   v = sl - 511; }
        else               { u = 255; v = sl - 765; }
        if (sum > 0.0f) {
            float df = sum - depth[(size_t)b * HWSZ + v * WW + u];
            s += df * df;
            c++;
        }
    }

    // ---- Part B: interior pixels from flat ----
    const float4* f4 = (const float4*)flat;
    const float4* z4 = (const float4*)depth;
    int total4 = B * (HWSZ / 4);
    for (int i = tid; i < total4; i += nthreads) {
        int l = i & (HWSZ / 4 - 1);
        int v = l >> 6;             // 64 quads per row
        if (v == 0 || v == 255) continue;   // whole row is border (Part A)
        int q = l & 63;
        float4 p = f4[i];
        float4 qd = z4[i];
        if (q == 0)  p.x = 0.0f;    // col-0 border pixel (Part A)
        if (q == 63) p.w = 0.0f;    // col-255 border pixel (Part A)
        if (p.x > 0.0f) { float df = p.x - qd.x; s += df * df; c++; }
        if (p.y > 0.0f) { float df = p.y - qd.y; s += df * df; c++; }
        if (p.z > 0.0f) { float df = p.z - qd.z; s += df * df; c++; }
        if (p.w > 0.0f) { float df = p.w - qd.w; s += df * df; c++; }
    }

    #pragma unroll
    for (int off = 32; off > 0; off >>= 1) {
        s += __shfl_down(s, off);
        c += __shfl_down(c, off);
    }
    if ((threadIdx.x & 63) == 0) {
        atomicAdd(accum, s);
        atomicAdd((int*)accum + 1, c);
    }
    __syncthreads();
    if (threadIdx.x == 0) {
        __threadfence();
        int old = atomicAdd(done, 1);
        if (old == nblocks - 1) {
            // L2-coherent reads of the final totals.
            float ts = atomicAdd(accum, 0.0f);
            int tc = atomicAdd((int*)accum + 1, 0);
            out[0] = ts / (float)(tc >= 1 ? tc : 1);
        }
    }
}

extern "C" void kernel_launch(void* const* d_in, const int* in_sizes, int n_in,
                              void* d_out, int out_size, void* d_ws, size_t ws_size,
                              hipStream_t stream) {
    const float* pts   = (const float*)d_in[0];  // (B, N, 3)
    const float* dens  = (const float*)d_in[1];  // (B, N, 1)
    const float* depth = (const float*)d_in[2];  // (B, 1, H, W)
    float* out = (float*)d_out;

    int B = in_sizes[2] / HWSZ;           // 8
    int N = in_sizes[0] / (3 * B);        // 500000

    int ngroups = N / 4;
    int cb = (ngroups + CHUNK_GROUPS - 1) / CHUNK_GROUPS;  // 245 blocks/batch

    float* flat    = (float*)d_ws;                     // B*HW floats
    float* accum   = flat + (size_t)B * HWSZ;          // [sum(float), count(int)]
    int*   done    = (int*)(accum + 2);
    float* scratch = accum + 4;                        // B*cb*SLOTPAD floats (~8 MB)

    // ws is re-poisoned to 0xAA before every launch: zero flat+accum+done.
    // scratch needs no zeroing (every slot is overwritten by scatter_k).
    hipMemsetAsync(d_ws, 0, ((size_t)B * HWSZ + 4) * sizeof(float), stream);

    dim3 sgrid(cb, B);
    scatter_k<<<sgrid, 256, 0, stream>>>(pts, dens, flat, scratch, N, cb);

    int lblocks = 256;
    loss_k<<<dim3(lblocks), 256, 0, stream>>>(flat, depth, scratch, accum, done,
                                              out, B, cb, lblocks);
}